// Round 1
// baseline (734.085 us; speedup 1.0000x reference)
//
#include <hip/hip_runtime.h>
#include <cstdint>
#include <cstddef>

// Shapes fixed by setup_inputs()
#define GRP 16
#define KD  2048
#define ND  2048
#define TD  16384

#define BM 128
#define BN 128
#define BK 32

typedef __bf16 bf16x8 __attribute__((ext_vector_type(8)));
typedef float  f32x4  __attribute__((ext_vector_type(4)));

__device__ __forceinline__ uint16_t f2bf(float f) {
  uint32_t u = __builtin_bit_cast(uint32_t, f);
  u += 0x7fffu + ((u >> 16) & 1u);   // round-to-nearest-even
  return (uint16_t)(u >> 16);
}

__device__ __forceinline__ void gload16(const void* g, void* l) {
  __builtin_amdgcn_global_load_lds((__attribute__((address_space(1))) void*)g,
                                   (__attribute__((address_space(3))) void*)l,
                                   16, 0, 0);
}

__device__ __forceinline__ int find_group(const int* tokens, int row0) {
  int g = GRP - 1, start = 0;
  for (int i = 0; i < GRP; ++i) {
    int sz = tokens[i];
    if (row0 < start + sz) { g = i; break; }
    start += sz;
  }
  return g;
}

// ---------------- kernel 1: hidden fp32 -> bf16 (straight) ----------------
__global__ __launch_bounds__(256) void h2bf_kernel(const float* __restrict__ in,
                                                   uint16_t* __restrict__ out) {
  const size_t idx = ((size_t)blockIdx.x * 256 + threadIdx.x) * 8;
  const float4 a = *(const float4*)(in + idx);
  const float4 b = *(const float4*)(in + idx + 4);
  uint4 p;
  p.x = (uint32_t)f2bf(a.x) | ((uint32_t)f2bf(a.y) << 16);
  p.y = (uint32_t)f2bf(a.z) | ((uint32_t)f2bf(a.w) << 16);
  p.z = (uint32_t)f2bf(b.x) | ((uint32_t)f2bf(b.y) << 16);
  p.w = (uint32_t)f2bf(b.z) | ((uint32_t)f2bf(b.w) << 16);
  *(uint4*)(out + idx) = p;
}

// ------- kernel 2: weight fp32 [G][K][N] -> bf16 [G][N][K] (transpose) -----
__global__ __launch_bounds__(256) void wtrans_kernel(const float* __restrict__ w,
                                                     uint16_t* __restrict__ wT) {
  __shared__ uint32_t tile[64][33];   // [n][k/2] packed bf16 pairs, +1 pad
  const int g  = blockIdx.z;
  const int n0 = blockIdx.x * 64;
  const int k0 = blockIdx.y * 64;
  const float* src = w + (size_t)g * KD * ND;
  uint16_t* dst = wT + (size_t)g * ND * KD;
  const int t = threadIdx.x;

  {
    const int kl = t >> 4;          // 0..15
    const int n4 = (t & 15) * 4;    // 0..60
    uint16_t* t16 = (uint16_t*)&tile[0][0];  // row stride 66 u16
    for (int kk = 0; kk < 4; ++kk) {
      const int k = kk * 16 + kl;
      const float4 v = *(const float4*)(src + (size_t)(k0 + k) * ND + n0 + n4);
      t16[(n4 + 0) * 66 + k] = f2bf(v.x);
      t16[(n4 + 1) * 66 + k] = f2bf(v.y);
      t16[(n4 + 2) * 66 + k] = f2bf(v.z);
      t16[(n4 + 3) * 66 + k] = f2bf(v.w);
    }
  }
  __syncthreads();
  {
    const int n  = t >> 2;
    const int kq = (t & 3) * 8;     // u32 units
    uint32_t v[8];
    for (int j = 0; j < 8; ++j) v[j] = tile[n][kq + j];
    uint32_t* o = (uint32_t*)(dst + (size_t)(n0 + n) * KD + k0) + kq;
    *(uint4*)(o + 0) = make_uint4(v[0], v[1], v[2], v[3]);
    *(uint4*)(o + 4) = make_uint4(v[4], v[5], v[6], v[7]);
  }
}

// -------- kernel 3: grouped bf16 MFMA GEMM (m97 structure) -----------------
// A: bf16 [T][K]; Bt: bf16 [G][N][K]; C: fp32 [T][N]
__global__ __launch_bounds__(256) void gemm_kernel(const uint16_t* __restrict__ A,
                                                   const uint16_t* __restrict__ Bt,
                                                   const int* __restrict__ tokens,
                                                   float* __restrict__ C) {
  __shared__ uint16_t Alds[BM * BK];  // [row][k], row stride 32 (64 B)
  __shared__ uint16_t Blds[BN * BK];  // [col][k]

  const int t    = threadIdx.x;
  const int n0   = blockIdx.x * BN;
  const int row0 = blockIdx.y * BM;

  // group of this row tile (tile never spans groups: sizes are multiples of BM)
  const int g = find_group(tokens, row0);
  const uint16_t* Bg = Bt + (size_t)g * ND * KD;

  const int lane = t & 63;
  const int wid  = t >> 6;
  const int wm   = wid & 1;
  const int wn   = wid >> 1;
  const int l16  = lane & 15;
  const int quad = lane >> 4;

  f32x4 acc[4][4] = {};

  // staging: 512 chunks of 16 B per tile; thread covers chunks t and t+256.
  // LDS dest = chunk*16 B — contiguous in lane order (global_load_lds rule).
  const int c1 = t, c2 = t + 256;
  const int r1 = c1 >> 2, ko1 = (c1 & 3) * 8;
  const int r2 = c2 >> 2, ko2 = (c2 & 3) * 8;
  const uint16_t* Ap1 = A  + (size_t)(row0 + r1) * KD + ko1;
  const uint16_t* Ap2 = A  + (size_t)(row0 + r2) * KD + ko2;
  const uint16_t* Bp1 = Bg + (size_t)(n0  + r1) * KD + ko1;
  const uint16_t* Bp2 = Bg + (size_t)(n0  + r2) * KD + ko2;
  uint16_t* Al1 = &Alds[c1 * 8];
  uint16_t* Al2 = &Alds[c2 * 8];
  uint16_t* Bl1 = &Blds[c1 * 8];
  uint16_t* Bl2 = &Blds[c2 * 8];

  for (int k0 = 0; k0 < KD; k0 += BK) {
    __syncthreads();
    gload16(Ap1 + k0, Al1);
    gload16(Ap2 + k0, Al2);
    gload16(Bp1 + k0, Bl1);
    gload16(Bp2 + k0, Bl2);
    __syncthreads();

    bf16x8 af[4], bfr[4];
    for (int mi = 0; mi < 4; ++mi)
      af[mi] = *(const bf16x8*)&Alds[(wm * 64 + mi * 16 + l16) * BK + quad * 8];
    for (int ni = 0; ni < 4; ++ni)
      bfr[ni] = *(const bf16x8*)&Blds[(wn * 64 + ni * 16 + l16) * BK + quad * 8];

    for (int mi = 0; mi < 4; ++mi)
      for (int ni = 0; ni < 4; ++ni)
        acc[mi][ni] = __builtin_amdgcn_mfma_f32_16x16x32_bf16(af[mi], bfr[ni],
                                                              acc[mi][ni], 0, 0, 0);
  }

  // epilogue: C/D layout col=lane&15, row=quad*4+r (m89/m91-verified)
  for (int mi = 0; mi < 4; ++mi) {
    const int m = row0 + wm * 64 + mi * 16 + quad * 4;
    for (int ni = 0; ni < 4; ++ni) {
      const int n = n0 + wn * 64 + ni * 16 + l16;
      for (int r = 0; r < 4; ++r)
        C[(size_t)(m + r) * ND + n] = acc[mi][ni][r];
    }
  }
}

// ------------- fallback: fp32 tiled GEMM (no workspace needed) -------------
__global__ __launch_bounds__(256) void fb_gemm(const float* __restrict__ A,
                                               const float* __restrict__ W,
                                               const int* __restrict__ tokens,
                                               float* __restrict__ C) {
  __shared__ float As[16][64];
  __shared__ float Bs[16][65];
  const int n0 = blockIdx.x * 64;
  const int m0 = blockIdx.y * 64;
  const int g = find_group(tokens, m0);
  const float* Wg = W + (size_t)g * KD * ND;
  const int tx = threadIdx.x & 15, ty = threadIdx.x >> 4;
  float acc[4][4] = {};
  for (int k0 = 0; k0 < KD; k0 += 16) {
    for (int e = threadIdx.x; e < 64 * 16; e += 256) {
      int m = e >> 4, k = e & 15;
      As[k][m] = A[(size_t)(m0 + m) * KD + k0 + k];
    }
    for (int e = threadIdx.x; e < 64 * 16; e += 256) {
      int n = e & 63, k = e >> 6;
      Bs[k][n] = Wg[(size_t)(k0 + k) * ND + n0 + n];
    }
    __syncthreads();
    for (int k = 0; k < 16; ++k)
      for (int i = 0; i < 4; ++i)
        for (int j = 0; j < 4; ++j)
          acc[i][j] += As[k][ty * 4 + i] * Bs[k][tx * 4 + j];
    __syncthreads();
  }
  for (int i = 0; i < 4; ++i)
    for (int j = 0; j < 4; ++j)
      C[(size_t)(m0 + ty * 4 + i) * ND + n0 + tx * 4 + j] = acc[i][j];
}

extern "C" void kernel_launch(void* const* d_in, const int* in_sizes, int n_in,
                              void* d_out, int out_size, void* d_ws, size_t ws_size,
                              hipStream_t stream) {
  const float* hidden = (const float*)d_in[0];
  const float* weight = (const float*)d_in[1];
  const int*   tokens = (const int*)d_in[4];
  float* out = (float*)d_out;

  const size_t needA = (size_t)TD * KD * 2;            // 64 MiB
  const size_t needB = (size_t)GRP * ND * KD * 2;      // 128 MiB

  if (ws_size >= needA + needB) {
    uint16_t* hB = (uint16_t*)d_ws;
    uint16_t* wT = (uint16_t*)((char*)d_ws + needA);
    h2bf_kernel<<<(int)(((size_t)TD * KD) / (256 * 8)), 256, 0, stream>>>(hidden, hB);
    wtrans_kernel<<<dim3(ND / 64, KD / 64, GRP), 256, 0, stream>>>(weight, wT);
    gemm_kernel<<<dim3(ND / BN, TD / BM), 256, 0, stream>>>(hB, wT, tokens, out);
  } else {
    fb_gemm<<<dim3(ND / 64, TD / 64), 256, 0, stream>>>(hidden, weight, tokens, out);
  }
}

// Round 2
// 675.995 us; speedup vs baseline: 1.0859x; 1.0859x over previous
//
#include <hip/hip_runtime.h>
#include <cstdint>
#include <cstddef>

// Shapes fixed by setup_inputs()
#define GRP 16
#define KD  2048
#define ND  2048
#define TD  16384

#define BM 128
#define BN 128
#define BK 64

typedef __bf16 bf16x8 __attribute__((ext_vector_type(8)));
typedef float  f32x4  __attribute__((ext_vector_type(4)));

__device__ __forceinline__ uint16_t f2bf(float f) {
  uint32_t u = __builtin_bit_cast(uint32_t, f);
  u += 0x7fffu + ((u >> 16) & 1u);   // round-to-nearest-even
  return (uint16_t)(u >> 16);
}

__device__ __forceinline__ void gload16(const void* g, void* l) {
  __builtin_amdgcn_global_load_lds((__attribute__((address_space(1))) void*)g,
                                   (__attribute__((address_space(3))) void*)l,
                                   16, 0, 0);
}

__device__ __forceinline__ int find_group(const int* tokens, int row0) {
  int g = GRP - 1, start = 0;
  for (int i = 0; i < GRP; ++i) {
    int sz = tokens[i];
    if (row0 < start + sz) { g = i; break; }
    start += sz;
  }
  return g;
}

// ---------------- kernel 1: hidden fp32 -> bf16 (straight) ----------------
__global__ __launch_bounds__(256) void h2bf_kernel(const float* __restrict__ in,
                                                   uint16_t* __restrict__ out) {
  const size_t idx = ((size_t)blockIdx.x * 256 + threadIdx.x) * 8;
  const float4 a = *(const float4*)(in + idx);
  const float4 b = *(const float4*)(in + idx + 4);
  uint4 p;
  p.x = (uint32_t)f2bf(a.x) | ((uint32_t)f2bf(a.y) << 16);
  p.y = (uint32_t)f2bf(a.z) | ((uint32_t)f2bf(a.w) << 16);
  p.z = (uint32_t)f2bf(b.x) | ((uint32_t)f2bf(b.y) << 16);
  p.w = (uint32_t)f2bf(b.z) | ((uint32_t)f2bf(b.w) << 16);
  *(uint4*)(out + idx) = p;
}

// ------- kernel 2: weight fp32 [G][K][N] -> bf16 [G][N][K] (transpose) -----
// Pack bf16 k-pairs into u32 in registers; all LDS ops vectorized.
__global__ __launch_bounds__(256) void wtrans_kernel(const float* __restrict__ w,
                                                     uint16_t* __restrict__ wT) {
  __shared__ uint32_t tile[64][33];   // [n][kpair], +1 u32 pad
  const int g  = blockIdx.z;
  const int n0 = blockIdx.x * 64;
  const int k0 = blockIdx.y * 64;
  const float* src = w + (size_t)g * KD * ND;
  uint16_t* dst = wT + (size_t)g * ND * KD;
  const int t = threadIdx.x;

  // phase 1: read 2 k-rows x 4 n, pack (k,k+1) bf16 pairs, vector ds_write_b32
  {
    const int k2 = t >> 4;          // k-pair index 0..15
    const int n4 = (t & 15) * 4;    // 0..60
    for (int half = 0; half < 2; ++half) {
      const int kp = half * 16 + k2;          // 0..31
      const int k  = kp * 2;
      const float4 v0 = *(const float4*)(src + (size_t)(k0 + k)     * ND + n0 + n4);
      const float4 v1 = *(const float4*)(src + (size_t)(k0 + k + 1) * ND + n0 + n4);
      tile[n4 + 0][kp] = (uint32_t)f2bf(v0.x) | ((uint32_t)f2bf(v1.x) << 16);
      tile[n4 + 1][kp] = (uint32_t)f2bf(v0.y) | ((uint32_t)f2bf(v1.y) << 16);
      tile[n4 + 2][kp] = (uint32_t)f2bf(v0.z) | ((uint32_t)f2bf(v1.z) << 16);
      tile[n4 + 3][kp] = (uint32_t)f2bf(v0.w) | ((uint32_t)f2bf(v1.w) << 16);
    }
  }
  __syncthreads();
  // phase 2: read 8 u32 (16 k) per thread via 2x ds_read_b128, 2x 16B stores
  {
    const int n  = t >> 2;
    const int kq = (t & 3) * 8;     // u32 units: 0,8,16,24
    const uint4 a = *(const uint4*)&tile[n][kq];
    const uint4 b = *(const uint4*)&tile[n][kq + 4];
    uint32_t* o = (uint32_t*)(dst + (size_t)(n0 + n) * KD + k0) + kq;
    *(uint4*)(o + 0) = a;
    *(uint4*)(o + 4) = b;
  }
}

// -------- kernel 3: grouped bf16 MFMA GEMM, BK=64, xor-swizzled LDS --------
// A: bf16 [T][K]; Bt: bf16 [G][N][K]; C: fp32 [T][N]
__global__ __launch_bounds__(256) void gemm_kernel(const uint16_t* __restrict__ A,
                                                   const uint16_t* __restrict__ Bt,
                                                   const int* __restrict__ tokens,
                                                   float* __restrict__ C) {
  __shared__ uint16_t Alds[BM * BK];  // [row][k], 8 chunks of 16B per row, xor-swizzled
  __shared__ uint16_t Blds[BN * BK];

  const int t    = threadIdx.x;
  const int n0   = blockIdx.x * BN;
  const int row0 = blockIdx.y * BM;

  const int g = find_group(tokens, row0);
  const uint16_t* Bg = Bt + (size_t)g * ND * KD;

  const int lane = t & 63;
  const int wid  = t >> 6;
  const int wm   = wid & 1;
  const int wn   = wid >> 1;
  const int l16  = lane & 15;
  const int quad = lane >> 4;

  f32x4 acc[4][4] = {};

  // Staging: 1024 chunks of 16 B per tile; thread covers chunks t+256*i.
  // LDS dest = chunk*16 (lane-contiguous, global_load_lds rule).
  // Global source chunk-in-row is XOR-swizzled by (row&7) so fragment-read
  // banks depend only on the physical chunk -> conflict-free reads.
  const uint16_t* Apt[4]; const uint16_t* Bpt[4];
  uint16_t *Al[4], *Bl[4];
  for (int i = 0; i < 4; ++i) {
    const int c = t + 256 * i;
    const int r = c >> 3;
    const int ko = ((c & 7) ^ (r & 7)) * 8;
    Apt[i] = A  + (size_t)(row0 + r) * KD + ko;
    Bpt[i] = Bg + (size_t)(n0  + r) * KD + ko;
    Al[i] = &Alds[c * 8];
    Bl[i] = &Blds[c * 8];
  }

  // Precompute fragment LDS offsets (u16 units) for both k-halves.
  int aoff[2][4], boff[2][4];
  for (int h = 0; h < 2; ++h) {
    for (int mi = 0; mi < 4; ++mi) {
      const int r = wm * 64 + mi * 16 + l16;
      aoff[h][mi] = r * BK + (((h * 4 + quad) ^ (r & 7)) * 8);
    }
    for (int ni = 0; ni < 4; ++ni) {
      const int r = wn * 64 + ni * 16 + l16;
      boff[h][ni] = r * BK + (((h * 4 + quad) ^ (r & 7)) * 8);
    }
  }

  for (int k0 = 0; k0 < KD; k0 += BK) {
    __syncthreads();
    for (int i = 0; i < 4; ++i) gload16(Apt[i] + k0, Al[i]);
    for (int i = 0; i < 4; ++i) gload16(Bpt[i] + k0, Bl[i]);
    __syncthreads();

    for (int h = 0; h < 2; ++h) {
      bf16x8 af[4], bfr[4];
      for (int mi = 0; mi < 4; ++mi) af[mi]  = *(const bf16x8*)&Alds[aoff[h][mi]];
      for (int ni = 0; ni < 4; ++ni) bfr[ni] = *(const bf16x8*)&Blds[boff[h][ni]];
      for (int mi = 0; mi < 4; ++mi)
        for (int ni = 0; ni < 4; ++ni)
          acc[mi][ni] = __builtin_amdgcn_mfma_f32_16x16x32_bf16(af[mi], bfr[ni],
                                                                acc[mi][ni], 0, 0, 0);
    }
  }

  // epilogue: C/D layout col=lane&15, row=quad*4+r (m89/m91-verified)
  for (int mi = 0; mi < 4; ++mi) {
    const int m = row0 + wm * 64 + mi * 16 + quad * 4;
    for (int ni = 0; ni < 4; ++ni) {
      const int n = n0 + wn * 64 + ni * 16 + l16;
      for (int r = 0; r < 4; ++r)
        C[(size_t)(m + r) * ND + n] = acc[mi][ni][r];
    }
  }
}

// ------------- fallback: fp32 tiled GEMM (no workspace needed) -------------
__global__ __launch_bounds__(256) void fb_gemm(const float* __restrict__ A,
                                               const float* __restrict__ W,
                                               const int* __restrict__ tokens,
                                               float* __restrict__ C) {
  __shared__ float As[16][64];
  __shared__ float Bs[16][65];
  const int n0 = blockIdx.x * 64;
  const int m0 = blockIdx.y * 64;
  const int g = find_group(tokens, m0);
  const float* Wg = W + (size_t)g * KD * ND;
  const int tx = threadIdx.x & 15, ty = threadIdx.x >> 4;
  float acc[4][4] = {};
  for (int k0 = 0; k0 < KD; k0 += 16) {
    for (int e = threadIdx.x; e < 64 * 16; e += 256) {
      int m = e >> 4, k = e & 15;
      As[k][m] = A[(size_t)(m0 + m) * KD + k0 + k];
    }
    for (int e = threadIdx.x; e < 64 * 16; e += 256) {
      int n = e & 63, k = e >> 6;
      Bs[k][n] = Wg[(size_t)(k0 + k) * ND + n0 + n];
    }
    __syncthreads();
    for (int k = 0; k < 16; ++k)
      for (int i = 0; i < 4; ++i)
        for (int j = 0; j < 4; ++j)
          acc[i][j] += As[k][ty * 4 + i] * Bs[k][tx * 4 + j];
    __syncthreads();
  }
  for (int i = 0; i < 4; ++i)
    for (int j = 0; j < 4; ++j)
      C[(size_t)(m0 + ty * 4 + i) * ND + n0 + tx * 4 + j] = acc[i][j];
}

extern "C" void kernel_launch(void* const* d_in, const int* in_sizes, int n_in,
                              void* d_out, int out_size, void* d_ws, size_t ws_size,
                              hipStream_t stream) {
  const float* hidden = (const float*)d_in[0];
  const float* weight = (const float*)d_in[1];
  const int*   tokens = (const int*)d_in[4];
  float* out = (float*)d_out;

  const size_t needA = (size_t)TD * KD * 2;            // 64 MiB
  const size_t needB = (size_t)GRP * ND * KD * 2;      // 128 MiB

  if (ws_size >= needA + needB) {
    uint16_t* hB = (uint16_t*)d_ws;
    uint16_t* wT = (uint16_t*)((char*)d_ws + needA);
    h2bf_kernel<<<(int)(((size_t)TD * KD) / (256 * 8)), 256, 0, stream>>>(hidden, hB);
    wtrans_kernel<<<dim3(ND / 64, KD / 64, GRP), 256, 0, stream>>>(weight, wT);
    gemm_kernel<<<dim3(ND / BN, TD / BM), 256, 0, stream>>>(hB, wT, tokens, out);
  } else {
    fb_gemm<<<dim3(ND / 64, TD / 64), 256, 0, stream>>>(hidden, weight, tokens, out);
  }
}